// Round 2
// baseline (137.930 us; speedup 1.0000x reference)
//
#include <hip/hip_runtime.h>

// Self-attention fwd, B=2 N=2048 H=16 D=64, fp32 in/out, bf16 MFMA compute.
// Round 9: fix the collapsed register pipeline of R8.
//   R8 evidence: VGPR_Count=80 < 112 (2 tile-buffers + qf + oa) -> compiler
//   sank the global loads to their uses, destroying the prefetch; every
//   STEP ate exposed L2 latency with only ~4 waves/SIMD resident.
// Changes:
//   1. Fully-unrolled main loop with __builtin_amdgcn_sched_barrier(0) at
//      each iteration top: [fence][STEP(buf)][LOADT(buf,it+2)] -> loads
//      cannot cross iteration boundaries, prefetch distance >= 1 STEP.
//      Loads stay plain C++ so the compiler still emits correct counted
//      vmcnt waits (its waitcnt insertion was never the problem).
//   2. 4-way key split (was 2): grid 2048 blocks, 16 tiles/wave,
//      __launch_bounds__(256,3) -> 12 waves/CU, combine = 3 zones in LDS.
//   3. prep rewritten: V transposed by direct 128B-coalesced global gather
//      (no LDS, no barrier), v_cvt_pk_bf16_f32 packing everywhere.
//
// MFMA 32x32x16 bf16 layouts (HW-verified):
//   A: A[m=lane&31][k=(lane>>5)*8+j]   B: B[k=(lane>>5)*8+j][n=lane&31]
//   C/D: D[row=(reg&3)+8*(reg>>2)+4*(lane>>5)][col=lane&31]
//
// Kt tile (32 keys): block kc(0..3), lane l, j=0..7 holds
//   K[key=tile*32+(l&31)][d=kc*16+(l>>5)*8+j]          (S^T = K*Q^T A-frag)
// Vt tile: block qq=dt*2+s (0..3), lane l: j=0..3 ->
//   V[key=tile*32+8s+4g+j][d=dt*32+nl]; j=4..7 -> key 16+8s+4g+(j-4)
//   (matches P^T packing: k-slot {0-3,4-7} <-> keys {8s..,16+8s..} per g)

typedef float  f32x4  __attribute__((ext_vector_type(4)));
typedef float  f32x16 __attribute__((ext_vector_type(16)));
typedef short  s16x8  __attribute__((ext_vector_type(8)));
typedef short  s16x4  __attribute__((ext_vector_type(4)));
typedef int    i32x4  __attribute__((ext_vector_type(4)));

#define QSCALE 0.18033688011112042f  /* log2(e)/8 : folds 1/sqrt(64) + exp2 */

__device__ __forceinline__ unsigned short bf16r(float f) {
    unsigned u = __builtin_bit_cast(unsigned, f);
    u += 0x7fffu + ((u >> 16) & 1u);          // round-to-nearest-even
    return (unsigned short)(u >> 16);
}

__device__ __forceinline__ s16x8 cvt8f_scaled(const float* p, float s) {
    f32x4 a = *(const f32x4*)p;
    f32x4 b = *(const f32x4*)(p + 4);
    s16x8 r;
#pragma unroll
    for (int i = 0; i < 4; ++i) {
        r[i]   = (short)bf16r(a[i] * s);
        r[i+4] = (short)bf16r(b[i] * s);
    }
    return r;
}

// pack two f32 -> bf16 pair (lo in [15:0], hi in [31:16]), single VALU op
__device__ __forceinline__ int cvtpk2(float lo, float hi) {
    int r;
    asm("v_cvt_pk_bf16_f32 %0, %1, %2" : "=v"(r) : "v"(lo), "v"(hi));
    return r;
}

// ---- prepass: emit fragment-ordered bf16 tile images for K and V --------
// No LDS, no barriers; every output 16B slot built straight from global.
__global__ void __launch_bounds__(256)
prep(const float* __restrict__ K, const float* __restrict__ V,
     unsigned short* __restrict__ Kt, unsigned short* __restrict__ Vt) {
    const int t = threadIdx.x, bid = blockIdx.x;
    const int bh = bid & 31, nb = bid >> 5;      // nb: 2 tiles of 32 keys
    const int b = bh >> 4, h = bh & 15;
    const size_t tile0 = ((size_t)bh * 64 + nb * 2) * 2048;   // shorts

    // K: [tile][kc][lane][8] — lane reads 8 consecutive d of one key row
#pragma unroll
    for (int i = 0; i < 2; ++i) {
        const int lin = i * 256 + t;             // coalesced slot order
        const int kbl = lin >> 8, rem = lin & 255;
        const int kc = rem >> 6, l = rem & 63;
        const int nl = l & 31, gg = l >> 5;
        const float* src = K + ((size_t)(b * 2048 + nb * 64 + kbl * 32 + nl)) * 1024
                             + h * 64 + kc * 16 + gg * 8;
        f32x4 a = *(const f32x4*)src;
        f32x4 c = *(const f32x4*)(src + 4);
        i32x4 o = { cvtpk2(a[0], a[1]), cvtpk2(a[2], a[3]),
                    cvtpk2(c[0], c[1]), cvtpk2(c[2], c[3]) };
        *(i32x4*)(Kt + tile0 + kbl * 2048 + kc * 512 + l * 8) = o;
    }

    // V: [tile][qq=dt*2+s][lane][8] — gather 8 keys at one d.
    // Per load instr: 32 consecutive nl -> 128B contiguous per key row.
#pragma unroll
    for (int i = 0; i < 2; ++i) {
        const int lin = i * 256 + t;
        const int kbl = lin >> 8, rem = lin & 255;
        const int qq = rem >> 6, l = rem & 63;
        const int dt = qq >> 1, s = qq & 1;
        const int nl = l & 31, gg = l >> 5;
        const float* vp0 = V + ((size_t)(b * 2048 + nb * 64 + kbl * 32 + 8 * s + 4 * gg)) * 1024
                             + h * 64 + dt * 32 + nl;
        float x0 = vp0[0],     x1 = vp0[1024],  x2 = vp0[2048],  x3 = vp0[3072];
        float x4 = vp0[16384], x5 = vp0[17408], x6 = vp0[18432], x7 = vp0[19456];
        i32x4 o = { cvtpk2(x0, x1), cvtpk2(x2, x3),
                    cvtpk2(x4, x5), cvtpk2(x6, x7) };
        *(i32x4*)(Vt + tile0 + kbl * 2048 + qq * 512 + l * 8) = o;
    }
}

// ---- main attention kernel ----------------------------------------------
// 2048 blocks x 4 waves. Block = one 32-query tile (q0 = (bid>>5)*32) of
// head bh = bid&31 (same-bh blocks land on one XCD: bid stride 32 -> L2
// locality for tiles). Wave w = key quarter ksel, 16 tiles of 32 keys.
__global__ void __launch_bounds__(256, 3)
attn_fwd(const float* __restrict__ Q, const unsigned short* __restrict__ Kt,
         const unsigned short* __restrict__ Vt, float* __restrict__ O)
{
    __shared__ __align__(16) float ex[3 * 64 * 36];   // 27.6KB combine zones

    const int t = threadIdx.x;
    const int ksel = t >> 6, lane = t & 63;
    const int g = lane >> 5, nl = lane & 31;

    const int bid = blockIdx.x;
    const int bh  = bid & 31, qb = bid >> 5;
    const int b   = bh >> 4,  h  = bh & 15;
    const int q0  = qb * 32;

    // Q B-frags (pre-scaled by log2e/8): q = q0 + nl
    s16x8 qf[4];
    {
        const float* qp = Q + ((size_t)(b * 2048 + q0 + nl)) * 1024 + h * 64 + g * 8;
#pragma unroll
        for (int kc = 0; kc < 4; ++kc)
            qf[kc] = cvt8f_scaled(qp + kc * 16, QSCALE);
    }

    // per-lane fragment pointers (16 tiles per key-quarter)
    const unsigned short* kp = Kt + (size_t)bh * 131072 + (size_t)ksel * 32768 + lane * 8;
    const unsigned short* vp = Vt + (size_t)bh * 131072 + (size_t)ksel * 32768 + lane * 8;

    f32x16 oa0 = {}, oa1 = {};                   // O^T accum, dt=0 / dt=1
    f32x4  lpv = {};                             // softmax denom partials

    s16x8 kfa[4], vfa[4], kfb[4], vfb[4];        // register double buffer

#define LOADT(KD, VD, IT) do {                                              \
        const unsigned short* _k = kp + (IT) * 2048;                        \
        const unsigned short* _v = vp + (IT) * 2048;                        \
        _Pragma("unroll")                                                   \
        for (int _i = 0; _i < 4; ++_i) {                                    \
            KD[_i] = *(const s16x8*)(_k + _i * 512);                        \
            VD[_i] = *(const s16x8*)(_v + _i * 512);                        \
        } } while (0)

#define STEP(KF, VF) do {                                                   \
        f32x16 sacc = {};                                                   \
        _Pragma("unroll")                                                   \
        for (int _kc = 0; _kc < 4; ++_kc)                                   \
            sacc = __builtin_amdgcn_mfma_f32_32x32x16_bf16(                 \
                KF[_kc], qf[_kc], sacc, 0, 0, 0);                           \
        int pk[8];                                                          \
        _Pragma("unroll")                                                   \
        for (int _c = 0; _c < 4; ++_c) {                                    \
            f32x4 e = { __builtin_amdgcn_exp2f(sacc[4*_c]),                 \
                        __builtin_amdgcn_exp2f(sacc[4*_c+1]),               \
                        __builtin_amdgcn_exp2f(sacc[4*_c+2]),               \
                        __builtin_amdgcn_exp2f(sacc[4*_c+3]) };             \
            lpv += e;                                                       \
            pk[2*_c]   = cvtpk2(e[0], e[1]);                                \
            pk[2*_c+1] = cvtpk2(e[2], e[3]);                                \
        }                                                                   \
        _Pragma("unroll")                                                   \
        for (int _s = 0; _s < 2; ++_s) {                                    \
            i32x4 bd = { pk[_s*2], pk[_s*2+1], pk[_s*2+4], pk[_s*2+5] };    \
            s16x8 bb = __builtin_bit_cast(s16x8, bd);                       \
            oa0 = __builtin_amdgcn_mfma_f32_32x32x16_bf16(VF[_s],     bb, oa0, 0, 0, 0); \
            oa1 = __builtin_amdgcn_mfma_f32_32x32x16_bf16(VF[2 + _s], bb, oa1, 0, 0, 0); \
        } } while (0)

    LOADT(kfa, vfa, 0);
    LOADT(kfb, vfb, 1);
#pragma unroll
    for (int it = 0; it < 16; ++it) {
        // Fence: nothing crosses an iteration boundary. Keeps LOADT(it+2)
        // issued in iteration `it` -> prefetch distance >= one full STEP
        // (defeats the live-range-shrinking sink that collapsed R8).
        __builtin_amdgcn_sched_barrier(0);
        if ((it & 1) == 0) {
            STEP(kfa, vfa);
            if (it + 2 < 16) LOADT(kfa, vfa, it + 2);
        } else {
            STEP(kfb, vfb);
            if (it + 2 < 16) LOADT(kfb, vfb, it + 2);
        }
    }
    __builtin_amdgcn_sched_barrier(0);
#undef LOADT
#undef STEP

    const float lp = lpv[0] + lpv[1] + lpv[2] + lpv[3];

    // ---- combine the 4 key quarters (pure add; softmax is max-free) ----
    if (ksel) {
        float* zone = ex + (ksel - 1) * 2304 + lane * 36;  // 144B stride
#pragma unroll
        for (int i = 0; i < 4; ++i) {
            *(f32x4*)(zone + i * 4) =
                (f32x4){ oa0[4*i], oa0[4*i+1], oa0[4*i+2], oa0[4*i+3] };
            *(f32x4*)(zone + 16 + i * 4) =
                (f32x4){ oa1[4*i], oa1[4*i+1], oa1[4*i+2], oa1[4*i+3] };
        }
        zone[32] = lp;
    }
    __syncthreads();
    if (!ksel) {
        float lps = lp;
#pragma unroll
        for (int z = 0; z < 3; ++z) {
            const float* zn = ex + z * 2304 + lane * 36;
#pragma unroll
            for (int i = 0; i < 4; ++i) {
                f32x4 u0 = *(const f32x4*)(zn + i * 4);
                f32x4 u1 = *(const f32x4*)(zn + 16 + i * 4);
#pragma unroll
                for (int j = 0; j < 4; ++j) { oa0[4*i+j] += u0[j]; oa1[4*i+j] += u1[j]; }
            }
            lps += zn[32];
        }
        float ssum = lps + __shfl_xor(lps, 32);  // opposite g-half's key rows
        const float inv = 1.0f / ssum;
        float* op = O + ((size_t)(b * 2048 + q0 + nl)) * 1024 + h * 64;
#pragma unroll
        for (int rq = 0; rq < 4; ++rq) {
            const int d0 = 8 * rq + 4 * g;
            *(f32x4*)(op + d0) = (f32x4){
                oa0[4*rq]   * inv, oa0[4*rq+1] * inv,
                oa0[4*rq+2] * inv, oa0[4*rq+3] * inv };
            *(f32x4*)(op + 32 + d0) = (f32x4){
                oa1[4*rq]   * inv, oa1[4*rq+1] * inv,
                oa1[4*rq+2] * inv, oa1[4*rq+3] * inv };
        }
    }
}

extern "C" void kernel_launch(void* const* d_in, const int* in_sizes, int n_in,
                              void* d_out, int out_size, void* d_ws, size_t ws_size,
                              hipStream_t stream) {
    const float* q = (const float*)d_in[0];
    const float* k = (const float*)d_in[1];
    const float* v = (const float*)d_in[2];
    float* o = (float*)d_out;

    unsigned short* Kt = (unsigned short*)d_ws;   // 8 MB fragment-ordered K tiles
    unsigned short* Vt = Kt + 4194304;            // 8 MB fragment-ordered V tiles

    hipLaunchKernelGGL(prep,     dim3(1024), dim3(256), 0, stream, k, v, Kt, Vt);
    hipLaunchKernelGGL(attn_fwd, dim3(2048), dim3(256), 0, stream, q, Kt, Vt, o);
}

// Round 4
// 137.741 us; speedup vs baseline: 1.0014x; 1.0014x over previous
//
#include <hip/hip_runtime.h>

// Self-attention fwd, B=2 N=2048 H=16 D=64, fp32 in/out, bf16 MFMA compute.
// Round 11: isolation experiment. R10 (asm loads + 64q restructure + raw
// s_barrier, all at once) produced NaN with no counters. This round takes
// the KNOWN-PASSING R9 kernel and changes exactly ONE thing: the tile
// loads become inline-asm global_load_dwordx4 into a register double
// buffer, ordered by hand-counted s_waitcnt vmcnt(8/0) + sched_barrier(0)
// (rule #18: MFMA hoists past asm waitcnt without the sched fence).
// Everything else (grid 2048, 32q/wave, 4-way ksel split, combine zones,
// prep) is byte-identical to the passing R9.
//   - R9's failure mode: compiler collapsed the C++ double buffer
//     (VGPR=84 < needed 112), exposing full L2 latency per STEP.
//   - Register budget: ~155 live <= 170 cap at __launch_bounds__(256,3),
//     so no spill -> the async-writeback/spill hazard cannot fire.
//   - Ledger: prologue issues tiles 0,1 (16 loads). Steady state:
//     WAITN(8) -> current tile's 8 loads done (vmcnt counts in issue
//     order), 8 outstanding (next tile). Tail: WAITN(8), WAITN(0).
//
// MFMA 32x32x16 bf16 layouts (HW-verified):
//   A: A[m=lane&31][k=(lane>>5)*8+j]   B: B[k=(lane>>5)*8+j][n=lane&31]
//   C/D: D[row=(reg&3)+8*(reg>>2)+4*(lane>>5)][col=lane&31]
//
// Kt tile (32 keys): block kc(0..3), lane l, j=0..7 holds
//   K[key=tile*32+(l&31)][d=kc*16+(l>>5)*8+j]          (S^T = K*Q^T A-frag)
// Vt tile: block qq=dt*2+s (0..3), lane l: j=0..3 ->
//   V[key=tile*32+8s+4g+j][d=dt*32+nl]; j=4..7 -> key 16+8s+4g+(j-4)
//   (matches P^T packing: k-slot {0-3,4-7} <-> keys {8s..,16+8s..} per g)

typedef float  f32x4  __attribute__((ext_vector_type(4)));
typedef float  f32x16 __attribute__((ext_vector_type(16)));
typedef short  s16x8  __attribute__((ext_vector_type(8)));
typedef short  s16x4  __attribute__((ext_vector_type(4)));
typedef int    i32x4  __attribute__((ext_vector_type(4)));

#define QSCALE 0.18033688011112042f  /* log2(e)/8 : folds 1/sqrt(64) + exp2 */

__device__ __forceinline__ unsigned short bf16r(float f) {
    unsigned u = __builtin_bit_cast(unsigned, f);
    u += 0x7fffu + ((u >> 16) & 1u);          // round-to-nearest-even
    return (unsigned short)(u >> 16);
}

__device__ __forceinline__ s16x8 cvt8f_scaled(const float* p, float s) {
    f32x4 a = *(const f32x4*)p;
    f32x4 b = *(const f32x4*)(p + 4);
    s16x8 r;
#pragma unroll
    for (int i = 0; i < 4; ++i) {
        r[i]   = (short)bf16r(a[i] * s);
        r[i+4] = (short)bf16r(b[i] * s);
    }
    return r;
}

// pack two f32 -> bf16 pair (lo in [15:0], hi in [31:16]), single VALU op
__device__ __forceinline__ int cvtpk2(float lo, float hi) {
    int r;
    asm("v_cvt_pk_bf16_f32 %0, %1, %2" : "=v"(r) : "v"(lo), "v"(hi));
    return r;
}

// ---- prepass: emit fragment-ordered bf16 tile images for K and V --------
// (identical to passing R9)
__global__ void __launch_bounds__(256)
prep(const float* __restrict__ K, const float* __restrict__ V,
     unsigned short* __restrict__ Kt, unsigned short* __restrict__ Vt) {
    const int t = threadIdx.x, bid = blockIdx.x;
    const int bh = bid & 31, nb = bid >> 5;      // nb: 2 tiles of 32 keys
    const int b = bh >> 4, h = bh & 15;
    const size_t tile0 = ((size_t)bh * 64 + nb * 2) * 2048;   // shorts

    // K: [tile][kc][lane][8] — lane reads 8 consecutive d of one key row
#pragma unroll
    for (int i = 0; i < 2; ++i) {
        const int lin = i * 256 + t;
        const int kbl = lin >> 8, rem = lin & 255;
        const int kc = rem >> 6, l = rem & 63;
        const int nl = l & 31, gg = l >> 5;
        const float* src = K + ((size_t)(b * 2048 + nb * 64 + kbl * 32 + nl)) * 1024
                             + h * 64 + kc * 16 + gg * 8;
        f32x4 a = *(const f32x4*)src;
        f32x4 c = *(const f32x4*)(src + 4);
        i32x4 o = { cvtpk2(a[0], a[1]), cvtpk2(a[2], a[3]),
                    cvtpk2(c[0], c[1]), cvtpk2(c[2], c[3]) };
        *(i32x4*)(Kt + tile0 + kbl * 2048 + kc * 512 + l * 8) = o;
    }

    // V: [tile][qq=dt*2+s][lane][8] — gather 8 keys at one d
#pragma unroll
    for (int i = 0; i < 2; ++i) {
        const int lin = i * 256 + t;
        const int kbl = lin >> 8, rem = lin & 255;
        const int qq = rem >> 6, l = rem & 63;
        const int dt = qq >> 1, s = qq & 1;
        const int nl = l & 31, gg = l >> 5;
        const float* vp0 = V + ((size_t)(b * 2048 + nb * 64 + kbl * 32 + 8 * s + 4 * gg)) * 1024
                             + h * 64 + dt * 32 + nl;
        float x0 = vp0[0],     x1 = vp0[1024],  x2 = vp0[2048],  x3 = vp0[3072];
        float x4 = vp0[16384], x5 = vp0[17408], x6 = vp0[18432], x7 = vp0[19456];
        i32x4 o = { cvtpk2(x0, x1), cvtpk2(x2, x3),
                    cvtpk2(x4, x5), cvtpk2(x6, x7) };
        *(i32x4*)(Vt + tile0 + kbl * 2048 + qq * 512 + l * 8) = o;
    }
}

// ---- main attention kernel ----------------------------------------------
// 2048 blocks x 4 waves. Block = one 32-query tile, wave = key quarter
// (16 tiles of 32 keys). Same shape as passing R9.
__global__ void __launch_bounds__(256, 3)
attn_fwd(const float* __restrict__ Q, const unsigned short* __restrict__ Kt,
         const unsigned short* __restrict__ Vt, float* __restrict__ O)
{
    __shared__ __align__(16) float ex[3 * 64 * 36];   // 27.6KB combine zones

    const int t = threadIdx.x;
    const int ksel = t >> 6, lane = t & 63;
    const int g = lane >> 5, nl = lane & 31;

    const int bid = blockIdx.x;
    const int bh  = bid & 31, qb = bid >> 5;
    const int b   = bh >> 4,  h  = bh & 15;
    const int q0  = qb * 32;

    // Q B-frags (pre-scaled by log2e/8): q = q0 + nl
    s16x8 qf[4];
    {
        const float* qp = Q + ((size_t)(b * 2048 + q0 + nl)) * 1024 + h * 64 + g * 8;
#pragma unroll
        for (int kc = 0; kc < 4; ++kc)
            qf[kc] = cvt8f_scaled(qp + kc * 16, QSCALE);
    }
    // Q loads + converts complete above; asm-load vmcnt ledger starts clean.
    __builtin_amdgcn_sched_barrier(0);

    // rolling per-lane tile pointers (advance 2048 shorts = 4KB per tile)
    const unsigned short* ka = Kt + (size_t)bh * 131072 + (size_t)ksel * 32768 + lane * 8;
    const unsigned short* va = Vt + (size_t)bh * 131072 + (size_t)ksel * 32768 + lane * 8;

    f32x16 oa0 = {}, oa1 = {};                   // O^T accum, dt=0 / dt=1
    f32x4  lpv = {};                             // softmax denom partials

    s16x8 kfa[4], vfa[4], kfb[4], vfb[4];        // asm-owned double buffer

#define GLD4(D, P)                                                          \
    asm volatile("global_load_dwordx4 %0, %4, off\n\t"                      \
                 "global_load_dwordx4 %1, %4, off offset:1024\n\t"          \
                 "global_load_dwordx4 %2, %4, off offset:2048\n\t"          \
                 "global_load_dwordx4 %3, %4, off offset:3072"              \
                 : "=&v"(D[0]), "=&v"(D[1]), "=&v"(D[2]), "=&v"(D[3])       \
                 : "v"(P))

#define ISSUE(KB, VB) do { GLD4(KB, ka); GLD4(VB, va);                      \
        ka += 2048; va += 2048; } while (0)

#define WAITN(N) do {                                                       \
        asm volatile("s_waitcnt vmcnt(" #N ")" ::: "memory");               \
        __builtin_amdgcn_sched_barrier(0); } while (0)

#define STEP(KF, VF) do {                                                   \
        f32x16 sacc = {};                                                   \
        _Pragma("unroll")                                                   \
        for (int _kc = 0; _kc < 4; ++_kc)                                   \
            sacc = __builtin_amdgcn_mfma_f32_32x32x16_bf16(                 \
                KF[_kc], qf[_kc], sacc, 0, 0, 0);                           \
        int pk[8];                                                          \
        _Pragma("unroll")                                                   \
        for (int _c = 0; _c < 4; ++_c) {                                    \
            f32x4 e = { __builtin_amdgcn_exp2f(sacc[4*_c]),                 \
                        __builtin_amdgcn_exp2f(sacc[4*_c+1]),               \
                        __builtin_amdgcn_exp2f(sacc[4*_c+2]),               \
                        __builtin_amdgcn_exp2f(sacc[4*_c+3]) };             \
            lpv += e;                                                       \
            pk[2*_c]   = cvtpk2(e[0], e[1]);                                \
            pk[2*_c+1] = cvtpk2(e[2], e[3]);                                \
        }                                                                   \
        _Pragma("unroll")                                                   \
        for (int _s = 0; _s < 2; ++_s) {                                    \
            i32x4 bd = { pk[_s*2], pk[_s*2+1], pk[_s*2+4], pk[_s*2+5] };    \
            s16x8 bb = __builtin_bit_cast(s16x8, bd);                       \
            oa0 = __builtin_amdgcn_mfma_f32_32x32x16_bf16(VF[_s],     bb, oa0, 0, 0, 0); \
            oa1 = __builtin_amdgcn_mfma_f32_32x32x16_bf16(VF[2 + _s], bb, oa1, 0, 0, 0); \
        } } while (0)

    ISSUE(kfa, vfa);                             // tile 0
    ISSUE(kfb, vfb);                             // tile 1   (16 outstanding)

    for (int n = 0; n < 7; ++n) {
        WAITN(8);                                // tile 2n resident
        STEP(kfa, vfa);
        __builtin_amdgcn_sched_barrier(0);       // STEP stays above reissue
        ISSUE(kfa, vfa);                         // tile 2n+2
        WAITN(8);                                // tile 2n+1 resident
        STEP(kfb, vfb);
        __builtin_amdgcn_sched_barrier(0);
        ISSUE(kfb, vfb);                         // tile 2n+3
    }
    WAITN(8);
    STEP(kfa, vfa);                              // tile 14
    WAITN(0);
    STEP(kfb, vfb);                              // tile 15

#undef GLD4
#undef ISSUE
#undef WAITN
#undef STEP

    const float lp = lpv[0] + lpv[1] + lpv[2] + lpv[3];

    // ---- combine the 4 key quarters (identical to passing R9) ----
    if (ksel) {
        float* zone = ex + (ksel - 1) * 2304 + lane * 36;  // 144B stride
#pragma unroll
        for (int i = 0; i < 4; ++i) {
            *(f32x4*)(zone + i * 4) =
                (f32x4){ oa0[4*i], oa0[4*i+1], oa0[4*i+2], oa0[4*i+3] };
            *(f32x4*)(zone + 16 + i * 4) =
                (f32x4){ oa1[4*i], oa1[4*i+1], oa1[4*i+2], oa1[4*i+3] };
        }
        zone[32] = lp;
    }
    __syncthreads();
    if (!ksel) {
        float lps = lp;
#pragma unroll
        for (int z = 0; z < 3; ++z) {
            const float* zn = ex + z * 2304 + lane * 36;
#pragma unroll
            for (int i = 0; i < 4; ++i) {
                f32x4 u0 = *(const f32x4*)(zn + i * 4);
                f32x4 u1 = *(const f32x4*)(zn + 16 + i * 4);
#pragma unroll
                for (int j = 0; j < 4; ++j) { oa0[4*i+j] += u0[j]; oa1[4*i+j] += u1[j]; }
            }
            lps += zn[32];
        }
        float ssum = lps + __shfl_xor(lps, 32);  // opposite g-half's key rows
        const float inv = 1.0f / ssum;
        float* op = O + ((size_t)(b * 2048 + q0 + nl)) * 1024 + h * 64;
#pragma unroll
        for (int rq = 0; rq < 4; ++rq) {
            const int d0 = 8 * rq + 4 * g;
            *(f32x4*)(op + d0) = (f32x4){
                oa0[4*rq]   * inv, oa0[4*rq+1] * inv,
                oa0[4*rq+2] * inv, oa0[4*rq+3] * inv };
            *(f32x4*)(op + 32 + d0) = (f32x4){
                oa1[4*rq]   * inv, oa1[4*rq+1] * inv,
                oa1[4*rq+2] * inv, oa1[4*rq+3] * inv };
        }
    }
}

extern "C" void kernel_launch(void* const* d_in, const int* in_sizes, int n_in,
                              void* d_out, int out_size, void* d_ws, size_t ws_size,
                              hipStream_t stream) {
    const float* q = (const float*)d_in[0];
    const float* k = (const float*)d_in[1];
    const float* v = (const float*)d_in[2];
    float* o = (float*)d_out;

    unsigned short* Kt = (unsigned short*)d_ws;   // 8 MB fragment-ordered K tiles
    unsigned short* Vt = Kt + 4194304;            // 8 MB fragment-ordered V tiles

    hipLaunchKernelGGL(prep,     dim3(1024), dim3(256), 0, stream, k, v, Kt, Vt);
    hipLaunchKernelGGL(attn_fwd, dim3(2048), dim3(256), 0, stream, q, Kt, Vt, o);
}

// Round 5
// 127.506 us; speedup vs baseline: 1.0818x; 1.0803x over previous
//
#include <hip/hip_runtime.h>

// Self-attention fwd, B=2 N=2048 H=16 D=64, fp32 in/out, bf16 MFMA compute.
// Round 12: 64 queries/wave with the SAFE (C++) load path.
//   R11 isolation result: asm register pipeline == R9 C++ pipeline (57.4 vs
//   58.8 us), VGPR_Count 84 both. Reinterpretation: 84 = 64 (double buffer)
//   + 16 (qf) + temps -- accumulators are in AGPRs (not counted). R9 was
//   never collapsed; latency/scheduling was NEVER the bottleneck. The real
//   limit is bytes/CU through the vector return path: 32q/wave pulls
//   1.07 GB L2->reg (~27 us return occupancy + ~31 us L2 floor).
//   Fix: amortize K/V over 64 queries/wave -> 537 MB total.
//   R10 (same shape, asm loads) NaN'd -- attributed to spill of asm-pending
//   load registers at ~207 regs (asm's sync model breaks under spill).
//   C++ loads are spill-safe (compiler models the dependency), and R8/R9
//   prove the compiler KEEPS the double buffer.
// Structure: 512 blocks x 4 waves (qsel = w&1, ksel = w>>1). Wave = 64
// queries (2 q-tiles of 32) x one key half (32 tiles of 32 keys). Register
// double-buffer + sched_barrier(0) iteration fences. Epilogue = R7's
// verified 2-zone combine (stride 68 floats). Prep identical to R9/R11.
//
// MFMA 32x32x16 bf16 layouts (HW-verified):
//   A: A[m=lane&31][k=(lane>>5)*8+j]   B: B[k=(lane>>5)*8+j][n=lane&31]
//   C/D: D[row=(reg&3)+8*(reg>>2)+4*(lane>>5)][col=lane&31]
//
// Kt tile (32 keys): block kc(0..3), lane l, j=0..7 holds
//   K[key=tile*32+(l&31)][d=kc*16+(l>>5)*8+j]          (S^T = K*Q^T A-frag)
// Vt tile: block qq=dt*2+s (0..3), lane l: j=0..3 ->
//   V[key=tile*32+8s+4g+j][d=dt*32+nl]; j=4..7 -> key 16+8s+4g+(j-4)
//   (matches P^T packing: k-slot {0-3,4-7} <-> keys {8s..,16+8s..} per g)

typedef float  f32x4  __attribute__((ext_vector_type(4)));
typedef float  f32x16 __attribute__((ext_vector_type(16)));
typedef short  s16x8  __attribute__((ext_vector_type(8)));
typedef short  s16x4  __attribute__((ext_vector_type(4)));
typedef int    i32x4  __attribute__((ext_vector_type(4)));

#define QSCALE 0.18033688011112042f  /* log2(e)/8 : folds 1/sqrt(64) + exp2 */

__device__ __forceinline__ unsigned short bf16r(float f) {
    unsigned u = __builtin_bit_cast(unsigned, f);
    u += 0x7fffu + ((u >> 16) & 1u);          // round-to-nearest-even
    return (unsigned short)(u >> 16);
}

__device__ __forceinline__ s16x8 cvt8f_scaled(const float* p, float s) {
    f32x4 a = *(const f32x4*)p;
    f32x4 b = *(const f32x4*)(p + 4);
    s16x8 r;
#pragma unroll
    for (int i = 0; i < 4; ++i) {
        r[i]   = (short)bf16r(a[i] * s);
        r[i+4] = (short)bf16r(b[i] * s);
    }
    return r;
}

// pack two f32 -> bf16 pair (lo in [15:0], hi in [31:16]), single VALU op
__device__ __forceinline__ int cvtpk2(float lo, float hi) {
    int r;
    asm("v_cvt_pk_bf16_f32 %0, %1, %2" : "=v"(r) : "v"(lo), "v"(hi));
    return r;
}

// ---- prepass: emit fragment-ordered bf16 tile images for K and V --------
// (identical to passing R9/R11)
__global__ void __launch_bounds__(256)
prep(const float* __restrict__ K, const float* __restrict__ V,
     unsigned short* __restrict__ Kt, unsigned short* __restrict__ Vt) {
    const int t = threadIdx.x, bid = blockIdx.x;
    const int bh = bid & 31, nb = bid >> 5;      // nb: 2 tiles of 32 keys
    const int b = bh >> 4, h = bh & 15;
    const size_t tile0 = ((size_t)bh * 64 + nb * 2) * 2048;   // shorts

    // K: [tile][kc][lane][8] — lane reads 8 consecutive d of one key row
#pragma unroll
    for (int i = 0; i < 2; ++i) {
        const int lin = i * 256 + t;
        const int kbl = lin >> 8, rem = lin & 255;
        const int kc = rem >> 6, l = rem & 63;
        const int nl = l & 31, gg = l >> 5;
        const float* src = K + ((size_t)(b * 2048 + nb * 64 + kbl * 32 + nl)) * 1024
                             + h * 64 + kc * 16 + gg * 8;
        f32x4 a = *(const f32x4*)src;
        f32x4 c = *(const f32x4*)(src + 4);
        i32x4 o = { cvtpk2(a[0], a[1]), cvtpk2(a[2], a[3]),
                    cvtpk2(c[0], c[1]), cvtpk2(c[2], c[3]) };
        *(i32x4*)(Kt + tile0 + kbl * 2048 + kc * 512 + l * 8) = o;
    }

    // V: [tile][qq=dt*2+s][lane][8] — gather 8 keys at one d
#pragma unroll
    for (int i = 0; i < 2; ++i) {
        const int lin = i * 256 + t;
        const int kbl = lin >> 8, rem = lin & 255;
        const int qq = rem >> 6, l = rem & 63;
        const int dt = qq >> 1, s = qq & 1;
        const int nl = l & 31, gg = l >> 5;
        const float* vp0 = V + ((size_t)(b * 2048 + nb * 64 + kbl * 32 + 8 * s + 4 * gg)) * 1024
                             + h * 64 + dt * 32 + nl;
        float x0 = vp0[0],     x1 = vp0[1024],  x2 = vp0[2048],  x3 = vp0[3072];
        float x4 = vp0[16384], x5 = vp0[17408], x6 = vp0[18432], x7 = vp0[19456];
        i32x4 o = { cvtpk2(x0, x1), cvtpk2(x2, x3),
                    cvtpk2(x4, x5), cvtpk2(x6, x7) };
        *(i32x4*)(Vt + tile0 + kbl * 2048 + qq * 512 + l * 8) = o;
    }
}

// ---- main attention kernel ----------------------------------------------
__global__ void __launch_bounds__(256, 2)
attn_fwd(const float* __restrict__ Q, const unsigned short* __restrict__ Kt,
         const unsigned short* __restrict__ Vt, float* __restrict__ O)
{
    __shared__ __align__(16) float ex[2 * 64 * 68];   // 34.8 KB combine zones

    const int t = threadIdx.x;
    const int w = t >> 6, lane = t & 63;
    const int g = lane >> 5, nl = lane & 31;
    const int qsel = w & 1, ksel = w >> 1;

    const int bid = blockIdx.x;
    const int bh  = bid & 31, qb = bid >> 5;     // XCD = bid&7 = bh&7: 2MB/XCD
    const int b   = bh >> 4,  h  = bh & 15;
    const int q0  = qb * 128 + qsel * 64;

    // Q B-frags (pre-scaled by log2e/8): qf[qt][kc], q = q0 + qt*32 + nl
    s16x8 qf[2][4];
#pragma unroll
    for (int qt = 0; qt < 2; ++qt) {
        const float* qp = Q + ((size_t)(b * 2048 + q0 + qt * 32 + nl)) * 1024
                            + h * 64 + g * 8;
#pragma unroll
        for (int kc = 0; kc < 4; ++kc)
            qf[qt][kc] = cvt8f_scaled(qp + kc * 16, QSCALE);
    }

    // rolling per-lane tile pointers (advance 2048 shorts = 4KB per tile)
    const unsigned short* ka = Kt + (size_t)bh * 131072 + (size_t)ksel * 65536 + lane * 8;
    const unsigned short* va = Vt + (size_t)bh * 131072 + (size_t)ksel * 65536 + lane * 8;

    f32x16 oa00 = {}, oa01 = {}, oa10 = {}, oa11 = {};  // oa[dt][qt]
    f32x4  lpv0 = {}, lpv1 = {};

    s16x8 kfa[4], vfa[4], kfb[4], vfb[4];        // register double buffer

#define LOADT(KD, VD) do {                                                  \
        _Pragma("unroll")                                                   \
        for (int _i = 0; _i < 4; ++_i) {                                    \
            KD[_i] = *(const s16x8*)(ka + _i * 512);                        \
            VD[_i] = *(const s16x8*)(va + _i * 512);                        \
        }                                                                   \
        ka += 2048; va += 2048; } while (0)

#define QKROW(KF, QFq, LPV, PK) do {                                        \
        f32x16 sacc = {};                                                   \
        _Pragma("unroll")                                                   \
        for (int _kc = 0; _kc < 4; ++_kc)                                   \
            sacc = __builtin_amdgcn_mfma_f32_32x32x16_bf16(                 \
                KF[_kc], QFq[_kc], sacc, 0, 0, 0);                          \
        _Pragma("unroll")                                                   \
        for (int _c = 0; _c < 4; ++_c) {                                    \
            f32x4 e = { __builtin_amdgcn_exp2f(sacc[4*_c]),                 \
                        __builtin_amdgcn_exp2f(sacc[4*_c+1]),               \
                        __builtin_amdgcn_exp2f(sacc[4*_c+2]),               \
                        __builtin_amdgcn_exp2f(sacc[4*_c+3]) };             \
            LPV += e;                                                       \
            PK[2*_c]   = cvtpk2(e[0], e[1]);                                \
            PK[2*_c+1] = cvtpk2(e[2], e[3]);                                \
        } } while (0)

#define STEP(KF, VF) do {                                                   \
        int pk0[8], pk1[8];                                                 \
        QKROW(KF, qf[0], lpv0, pk0);                                        \
        QKROW(KF, qf[1], lpv1, pk1);                                        \
        _Pragma("unroll")                                                   \
        for (int _s = 0; _s < 2; ++_s) {                                    \
            i32x4 b0 = { pk0[_s*2], pk0[_s*2+1], pk0[_s*2+4], pk0[_s*2+5] };\
            i32x4 b1 = { pk1[_s*2], pk1[_s*2+1], pk1[_s*2+4], pk1[_s*2+5] };\
            s16x8 bb0 = __builtin_bit_cast(s16x8, b0);                      \
            s16x8 bb1 = __builtin_bit_cast(s16x8, b1);                      \
            oa00 = __builtin_amdgcn_mfma_f32_32x32x16_bf16(VF[_s],     bb0, oa00, 0, 0, 0); \
            oa10 = __builtin_amdgcn_mfma_f32_32x32x16_bf16(VF[2 + _s], bb0, oa10, 0, 0, 0); \
            oa01 = __builtin_amdgcn_mfma_f32_32x32x16_bf16(VF[_s],     bb1, oa01, 0, 0, 0); \
            oa11 = __builtin_amdgcn_mfma_f32_32x32x16_bf16(VF[2 + _s], bb1, oa11, 0, 0, 0); \
        } } while (0)

    LOADT(kfa, vfa);                             // tile 0
    LOADT(kfb, vfb);                             // tile 1

    for (int n = 0; n < 15; ++n) {
        // Fences pin issue order: [STEP a][LOAD a+2] | [STEP b][LOAD b+2].
        // Loads of tile 2n+2 are issued before STEP(b)'s compute -> they
        // fly under it (>= 1 full STEP of latency cover). Compiler inserts
        // the counted vmcnt waits (R9 proved it keeps the double buffer).
        __builtin_amdgcn_sched_barrier(0);
        STEP(kfa, vfa);                          // tile 2n
        LOADT(kfa, vfa);                         // tile 2n+2
        __builtin_amdgcn_sched_barrier(0);
        STEP(kfb, vfb);                          // tile 2n+1
        LOADT(kfb, vfb);                         // tile 2n+3
    }
    __builtin_amdgcn_sched_barrier(0);
    STEP(kfa, vfa);                              // tile 30
    STEP(kfb, vfb);                              // tile 31

#undef LOADT
#undef QKROW
#undef STEP

    float lp[2] = { lpv0[0] + lpv0[1] + lpv0[2] + lpv0[3],
                    lpv1[0] + lpv1[1] + lpv1[2] + lpv1[3] };

    // ---- combine key halves (pure add; softmax is max-free) ----
    __syncthreads();                             // all waves done with tiles
    float* zone = ex + qsel * (64 * 68) + lane * 68;   // 272B stride: aligned
    if (ksel) {
#pragma unroll
        for (int i = 0; i < 4; ++i) {
            *(f32x4*)(zone + i * 4) =
                (f32x4){ oa00[4*i], oa00[4*i+1], oa00[4*i+2], oa00[4*i+3] };
            *(f32x4*)(zone + 16 + i * 4) =
                (f32x4){ oa01[4*i], oa01[4*i+1], oa01[4*i+2], oa01[4*i+3] };
            *(f32x4*)(zone + 32 + i * 4) =
                (f32x4){ oa10[4*i], oa10[4*i+1], oa10[4*i+2], oa10[4*i+3] };
            *(f32x4*)(zone + 48 + i * 4) =
                (f32x4){ oa11[4*i], oa11[4*i+1], oa11[4*i+2], oa11[4*i+3] };
        }
        zone[64] = lp[0];
        zone[65] = lp[1];
    }
    __syncthreads();
    if (!ksel) {
#pragma unroll
        for (int i = 0; i < 4; ++i) {
            f32x4 u0 = *(const f32x4*)(zone + i * 4);
            f32x4 u1 = *(const f32x4*)(zone + 16 + i * 4);
            f32x4 u2 = *(const f32x4*)(zone + 32 + i * 4);
            f32x4 u3 = *(const f32x4*)(zone + 48 + i * 4);
#pragma unroll
            for (int j = 0; j < 4; ++j) {
                oa00[4*i+j] += u0[j]; oa01[4*i+j] += u1[j];
                oa10[4*i+j] += u2[j]; oa11[4*i+j] += u3[j];
            }
        }
        float inv[2];
#pragma unroll
        for (int qt = 0; qt < 2; ++qt) {
            float s = lp[qt] + zone[64 + qt];
            s += __shfl_xor(s, 32);              // opposite g-half's keys
            inv[qt] = 1.0f / s;
        }
        float* op0 = O + ((size_t)(b * 2048 + q0 + nl)) * 1024 + h * 64;
        float* op1 = op0 + 32 * 1024;            // q0 + 32 + nl
#pragma unroll
        for (int rq = 0; rq < 4; ++rq) {
            const int d0 = 8 * rq + 4 * g;
            *(f32x4*)(op0 + d0) = (f32x4){
                oa00[4*rq]   * inv[0], oa00[4*rq+1] * inv[0],
                oa00[4*rq+2] * inv[0], oa00[4*rq+3] * inv[0] };
            *(f32x4*)(op0 + 32 + d0) = (f32x4){
                oa10[4*rq]   * inv[0], oa10[4*rq+1] * inv[0],
                oa10[4*rq+2] * inv[0], oa10[4*rq+3] * inv[0] };
            *(f32x4*)(op1 + d0) = (f32x4){
                oa01[4*rq]   * inv[1], oa01[4*rq+1] * inv[1],
                oa01[4*rq+2] * inv[1], oa01[4*rq+3] * inv[1] };
            *(f32x4*)(op1 + 32 + d0) = (f32x4){
                oa11[4*rq]   * inv[1], oa11[4*rq+1] * inv[1],
                oa11[4*rq+2] * inv[1], oa11[4*rq+3] * inv[1] };
        }
    }
}

extern "C" void kernel_launch(void* const* d_in, const int* in_sizes, int n_in,
                              void* d_out, int out_size, void* d_ws, size_t ws_size,
                              hipStream_t stream) {
    const float* q = (const float*)d_in[0];
    const float* k = (const float*)d_in[1];
    const float* v = (const float*)d_in[2];
    float* o = (float*)d_out;

    unsigned short* Kt = (unsigned short*)d_ws;   // 8 MB fragment-ordered K tiles
    unsigned short* Vt = Kt + 4194304;            // 8 MB fragment-ordered V tiles

    hipLaunchKernelGGL(prep,     dim3(1024), dim3(256), 0, stream, k, v, Kt, Vt);
    hipLaunchKernelGGL(attn_fwd, dim3(512),  dim3(256), 0, stream, q, Kt, Vt, o);
}